// Round 5
// baseline (4658.048 us; speedup 1.0000x reference)
//
#include <hip/hip_runtime.h>
#include <math.h>

#define L 50
#define ML 64
#define VOCAB 32000
#define EMBED 1024
#define HID 1024
#define HH 512
#define TOT (VOCAB+ML)
#define NPART 501

// workspace layout (float offsets)
#define WS_ENC_GATES 0        // [2][4096]
#define WS_C_ENC     8192     // [2][1024]
#define WS_ENC_OUTS  10240    // [64][1024]
#define WS_COPY_ENC  75776    // [64][1024]
#define WS_H_DEC     141312   // [2][1024]
#define WS_C_DEC     143360   // [2][1024]
#define WS_X_DEC     145408   // [3072]
#define WS_DGATES    148480   // [4096]
#define WS_LOGITS    152576   // [32064]
#define WS_PARTS     184640   // [501*4] {lmax,sumexp,bestkey,bestidx}
#define WS_PREG      186880   // [50][4096] encoder input-side pregates (optional)
#define WS_PREG_END  (186880+50*4096)

__device__ __forceinline__ float wred_sum(float v){
  #pragma unroll
  for(int o=32;o;o>>=1) v += __shfl_xor(v,o,64);
  return v;
}
__device__ __forceinline__ float wred_max(float v){
  #pragma unroll
  for(int o=32;o;o>>=1) v = fmaxf(v,__shfl_xor(v,o,64));
  return v;
}
__device__ __forceinline__ float sigm(float x){ return 1.0f/(1.0f+__expf(-x)); }
__device__ __forceinline__ float d4(float4 a, float4 b){ return a.x*b.x + a.y*b.y + a.z*b.z + a.w*b.w; }

// ================= encoder pre-pass: pregates[t][r] = Wih_x . xemb_t + bias =================
__global__ __launch_bounds__(256) void k_enc_pre(
  const int* __restrict__ xt, const float* __restrict__ emb,
  const float* __restrict__ Wih_f, const float* __restrict__ bih_f, const float* __restrict__ bhh_f,
  const float* __restrict__ Wih_b, const float* __restrict__ bih_b, const float* __restrict__ bhh_b,
  float* __restrict__ ws)
{
  __shared__ __align__(16) float xe[1024];
  const int tid=threadIdx.x, b=blockIdx.x, wave=tid>>6, lane=tid&63;
  float* pg = ws + WS_PREG;
  float4 wih[2][4]; float bias[2];
  #pragma unroll
  for(int rr=0;rr<2;rr++){
    int r=b*8+wave*2+rr; bool isF=(r<2048); int rl=isF?r:(r-2048);
    const float* wp=(isF?Wih_f:Wih_b)+(size_t)rl*EMBED;
    #pragma unroll
    for(int c4=0;c4<4;c4++) wih[rr][c4]=*(const float4*)(wp+c4*256+lane*4);
    bias[rr]= isF?(bih_f[rl]+bhh_f[rl]):(bih_b[rl]+bhh_b[rl]);
  }
  for(int t=0;t<L;t++){
    const float* er = emb + (size_t)xt[t]*EMBED;
    for(int j=tid;j<1024;j+=256) xe[j]=er[j];
    __syncthreads();
    #pragma unroll
    for(int rr=0;rr<2;rr++){
      int r=b*8+wave*2+rr;
      float acc=0.0f;
      #pragma unroll
      for(int c4=0;c4<4;c4++) acc += d4(wih[rr][c4], *(const float4*)(&xe[c4*256+lane*4]));
      acc=wred_sum(acc);
      if(lane==0) pg[(size_t)t*4096+r]=acc+bias[rr];
    }
    __syncthreads();
  }
}

// ================= encoder recurrent step: cell-update(t-1) + Whh.h + pregates =================
__global__ __launch_bounds__(256) void k_enc_rec(
  const float* __restrict__ Whh_f, const float* __restrict__ Whh_b,
  float* __restrict__ ws, int t)
{
  __shared__ __align__(16) float h_lds[1024];
  const int tid=threadIdx.x, b=blockIdx.x, wave=tid>>6, lane=tid&63;
  float* gates   = ws + WS_ENC_GATES;
  float* c_enc   = ws + WS_C_ENC;
  float* enc_outs= ws + WS_ENC_OUTS;
  const float* pg = ws + WS_PREG + (size_t)t*4096;
  if(t>0){
    const float* gp = gates + ((t-1)&1)*4096;
    const float* cp = c_enc + (t&1)*1024;        // c_{t-2}
    float* cw = c_enc + ((t-1)&1)*1024;          // c_{t-1}
    for(int u=tid;u<1024;u+=256){
      int base=(u<512)?0:2048, uu=(u<512)?u:(u-512);
      float ig=gp[base+uu], fg=gp[base+512+uu], gg=gp[base+1024+uu], og=gp[base+1536+uu];
      float cprev=(t==1)?0.0f:cp[u];
      float c=sigm(fg)*cprev+sigm(ig)*tanhf(gg);
      float h=sigm(og)*tanhf(c);
      h_lds[u]=h;
      if(b==0){ cw[u]=c; enc_outs[(size_t)(t-1)*1024+u]=h; }
    }
  }
  __syncthreads();
  float* gw = gates + (t&1)*4096;
  #pragma unroll
  for(int rr=0;rr<2;rr++){
    int r=b*8+wave*2+rr; bool isF=(r<2048); int rl=isF?r:(r-2048);
    if(t==0){
      if(lane==0) gw[r]=pg[r];
    } else {
      const float* hr=(isF?Whh_f:Whh_b)+(size_t)rl*HH;
      const float* hs=&h_lds[isF?0:512];
      float acc=0.0f;
      #pragma unroll
      for(int c2=0;c2<2;c2++){
        int m=c2*256+lane*4;
        acc += d4(*(const float4*)(hr+m), *(const float4*)(&hs[m]));
      }
      acc=wred_sum(acc);
      if(lane==0) gw[r]=pg[r]+acc;
    }
  }
}

// ================= fallback encoder step (full GEMV, round-4 proven) =================
__global__ __launch_bounds__(256) void k_enc_step(
  const int* __restrict__ xt, const float* __restrict__ emb,
  const float* __restrict__ Wih_f, const float* __restrict__ Whh_f,
  const float* __restrict__ bih_f, const float* __restrict__ bhh_f,
  const float* __restrict__ Wih_b, const float* __restrict__ Whh_b,
  const float* __restrict__ bih_b, const float* __restrict__ bhh_b,
  float* __restrict__ ws, int t)
{
  __shared__ __align__(16) float h_lds[1024];
  __shared__ __align__(16) float xe[1024];
  const int tid = threadIdx.x;
  float* gates   = ws + WS_ENC_GATES;
  float* c_enc   = ws + WS_C_ENC;
  float* enc_outs= ws + WS_ENC_OUTS;
  {
    const int tok = xt[t];
    const float* er = emb + (size_t)tok*EMBED;
    for(int j=tid;j<1024;j+=256) xe[j]=er[j];
  }
  if(t>0){
    const float* gp = gates + ((t-1)&1)*4096;
    const float* cp = c_enc + (t&1)*1024;
    float* cw = c_enc + ((t-1)&1)*1024;
    for(int u=tid;u<1024;u+=256){
      int base=(u<512)?0:2048, uu=(u<512)?u:(u-512);
      float ig=gp[base+uu], fg=gp[base+512+uu], gg=gp[base+1024+uu], og=gp[base+1536+uu];
      float cprev=(t==1)?0.0f:cp[u];
      float c=sigm(fg)*cprev+sigm(ig)*tanhf(gg);
      float h=sigm(og)*tanhf(c);
      h_lds[u]=h;
      if(blockIdx.x==0){ cw[u]=c; enc_outs[(size_t)(t-1)*1024+u]=h; }
    }
  }
  __syncthreads();
  float* gw = gates + (t&1)*4096;
  const int wave=tid>>6, lane=tid&63;
  for(int rr=0;rr<2;rr++){
    int r=blockIdx.x*8+wave*2+rr;
    bool isF=(r<2048); int rl=isF?r:(r-2048);
    const float* Wih=isF?Wih_f:Wih_b;
    const float* Whh=isF?Whh_f:Whh_b;
    float bias=isF?(bih_f[rl]+bhh_f[rl]):(bih_b[rl]+bhh_b[rl]);
    const float* wr=Wih+(size_t)rl*EMBED;
    float acc=0.0f;
    #pragma unroll
    for(int c4=0;c4<4;c4++){
      int m=c4*256+lane*4;
      acc += d4(*(const float4*)(wr+m), *(const float4*)(&xe[m]));
    }
    if(t>0){
      const float* hr=Whh+(size_t)rl*HH;
      const float* hs=&h_lds[isF?0:512];
      #pragma unroll
      for(int c2=0;c2<2;c2++){
        int m=c2*256+lane*4;
        acc += d4(*(const float4*)(hr+m), *(const float4*)(&hs[m]));
      }
    }
    acc=wred_sum(acc);
    if(lane==0) gw[r]=acc+bias;
  }
}

// ================= k_copy_final: final cell update + handoff + pad zero + x_dec init + copy_enc =================
__global__ __launch_bounds__(256) void k_copy_final(
  const float* __restrict__ emb,
  const float* __restrict__ copy_W, const float* __restrict__ copy_b,
  float* __restrict__ ws, float* __restrict__ out)
{
  __shared__ __align__(16) float hf[1024];
  const int tid=threadIdx.x, b=blockIdx.x, wave=tid>>6, lane=tid&63;
  float* gates = ws + WS_ENC_GATES;
  float* c_enc = ws + WS_C_ENC;
  float* enc_outs = ws + WS_ENC_OUTS;
  float* cenc = ws + WS_COPY_ENC;
  float* h_dec = ws + WS_H_DEC;
  float* c_dec = ws + WS_C_DEC;
  float* x_dec = ws + WS_X_DEC;
  // final cell update (redundant per block; identical math -> identical values)
  {
    const float* gp = gates + ((L-1)&1)*4096;  // gates_49
    const float* cp = c_enc + ((L-2)&1)*1024;  // c_48
    for(int u=tid;u<1024;u+=256){
      int base=(u<512)?0:2048, uu=(u<512)?u:(u-512);
      float ig=gp[base+uu], fg=gp[base+512+uu], gg=gp[base+1024+uu], og=gp[base+1536+uu];
      float c=sigm(fg)*cp[u]+sigm(ig)*tanhf(gg);
      float h=sigm(og)*tanhf(c);
      hf[u]=h;
      if(b==0){
        enc_outs[(size_t)(L-1)*1024+u]=h;
        h_dec[1024+u]=h;   // h0 (parity-1)
        c_dec[1024+u]=c;   // c0 (parity-1)
        out[u]=h;          // states[0]
      }
    }
    if(b==1) for(int j=tid;j<(ML-L)*1024;j+=256) enc_outs[(size_t)L*1024+j]=0.0f;
    if(b==2) for(int j=tid;j<1024;j+=256){
      x_dec[j]=emb[j];          // sos = embedding[0]
      x_dec[1024+j]=0.0f;       // selective (first)
      x_dec[2048+j]=0.0f;       // attentive (first)
    }
  }
  __syncthreads();
  // copy_enc GEMV: row j per wave
  int j = b*4 + wave;
  const float* wr = copy_W + (size_t)j*1024;
  float4 w0=*(const float4*)(wr+0*256+lane*4);
  float4 w1=*(const float4*)(wr+1*256+lane*4);
  float4 w2=*(const float4*)(wr+2*256+lane*4);
  float4 w3=*(const float4*)(wr+3*256+lane*4);
  float bj = copy_b[j];
  for(int k=0;k<L-1;k++){
    const float* er = enc_outs + (size_t)k*1024;
    float acc = d4(w0,*(const float4*)(er+0*256+lane*4))
              + d4(w1,*(const float4*)(er+1*256+lane*4))
              + d4(w2,*(const float4*)(er+2*256+lane*4))
              + d4(w3,*(const float4*)(er+3*256+lane*4));
    acc = wred_sum(acc);
    if(lane==0) cenc[(size_t)k*1024+j]=tanhf(acc+bj);
  }
  {
    // k = 49 from LDS (identical value to ws copy)
    float acc = d4(w0,*(const float4*)(&hf[0*256+lane*4]))
              + d4(w1,*(const float4*)(&hf[1*256+lane*4]))
              + d4(w2,*(const float4*)(&hf[2*256+lane*4]))
              + d4(w3,*(const float4*)(&hf[3*256+lane*4]));
    acc = wred_sum(acc);
    if(lane==0) cenc[(size_t)(L-1)*1024+j]=tanhf(acc+bj);
  }
  if(lane==0){
    float z=tanhf(0.0f+bj);
    for(int k=L;k<ML;k++) cenc[(size_t)k*1024+j]=z;
  }
}

// ================= k_attn_prep: finalize step t-1 + pc + ALL attn rows + softmax + x_dec =================
// grid=64 (or 1 with fin_only=1). Every block computes everything redundantly (identical);
// block 0 writes outputs + x_dec[0:1024]; block b writes x_dec slice j in [b*16,(b+1)*16).
__global__ __launch_bounds__(256) void k_attn_prep(
  const int* __restrict__ xt, const float* __restrict__ amask,
  const float* __restrict__ emb,
  const float* __restrict__ attn_W, const float* __restrict__ attn_b,
  float* __restrict__ ws, float* __restrict__ out, int t, int fin_only)
{
  __shared__ __align__(16) float dec_in[1024];
  __shared__ __align__(16) float hprev[1024];
  __shared__ float r_lm[256], r_sm[256], r_ky[256];
  __shared__ int r_ix[256];
  __shared__ float attw_raw[64], attw_s[64], pc_s[64];
  __shared__ float s_lmax, s_Z;
  __shared__ int s_act;
  const int tid=threadIdx.x, b=blockIdx.x, wave=tid>>6, lane=tid&63;
  float* h_dec=ws+WS_H_DEC; float* x_dec=ws+WS_X_DEC;
  float* logits=ws+WS_LOGITS; float* parts=ws+WS_PARTS;
  float* enc_outs=ws+WS_ENC_OUTS;

  // ---- finalize step t-1 (identical per block) ----
  {
    float lm=-INFINITY, sm=0.0f, ky=-INFINITY; int ix=0x7fffffff;
    for(int i=tid;i<NPART;i+=256){
      const float4 p = *(const float4*)(parts+(size_t)i*4);
      float plm=p.x, psm=p.y, pky=p.z; int pix=__float_as_int(p.w);
      if(plm>lm){ sm = sm*__expf(lm-plm)+psm; lm=plm; }
      else sm += psm*__expf(plm-lm);
      if(pky>ky || (pky==ky && pix<ix)){ ky=pky; ix=pix; }
    }
    r_lm[tid]=lm; r_sm[tid]=sm; r_ky[tid]=ky; r_ix[tid]=ix;
    __syncthreads();
    for(int s=128;s;s>>=1){
      if(tid<s){
        float blm=r_lm[tid+s], bsm=r_sm[tid+s];
        float alm=r_lm[tid], a_sm=r_sm[tid];
        if(blm>alm){ r_sm[tid]=a_sm*__expf(alm-blm)+bsm; r_lm[tid]=blm; }
        else r_sm[tid]=a_sm+bsm*__expf(blm-alm);
        float bky=r_ky[tid+s]; int bix=r_ix[tid+s];
        if(bky>r_ky[tid] || (bky==r_ky[tid] && bix<r_ix[tid])){ r_ky[tid]=bky; r_ix[tid]=bix; }
      }
      __syncthreads();
    }
    if(tid==0){
      float lmax=r_lm[0]; float Z=r_sm[0];
      float bky=r_ky[0];
      int aidx = (bky==-INFINITY)?0:r_ix[0];
      bool isv = aidx<VOCAB;
      int kcl = aidx-VOCAB; kcl = kcl<0?0:(kcl>(L-1)?(L-1):kcl);
      int sp = xt[kcl];
      int action = isv? aidx : sp;
      if(b==0){
        float prob = amask[aidx]*__expf(logits[aidx]-lmax)/Z;
        if(!isv){
          int a2 = action<0?0:(action>(VOCAB-1)?(VOCAB-1):action);
          prob += amask[a2]*__expf(logits[a2]-lmax)/Z;
        }
        out[65*1024 + (t-1)] = prob;
        out[65*1024 + 64 + (t-1)] = (float)action;
      }
      s_lmax=lmax; s_Z=Z; s_act=action;
    }
  }
  __syncthreads();
  if(fin_only) return;

  const int action = s_act;
  // pc (redundant per block, identical)
  if(tid<64){
    int k=tid;
    float v=__expf(logits[VOCAB+k]-s_lmax)/s_Z;
    int sp=(k<L)? xt[k] : -1;
    float m=(k>=1 && k<(L-1) && sp!=action)?1.0f:0.0f;
    float pv=v*m;
    float s=wred_sum(pv);
    pc_s[k]=(s>0.0f)? pv/s : pv;
  }
  // dec_in + hprev into LDS
  {
    int row = action<0 ? action+VOCAB : action;
    const float* er = emb + (size_t)row*EMBED;
    const float* hp = h_dec + ((t-1)&1)*1024;
    for(int j=tid;j<1024;j+=256){
      float v=er[j];
      dec_in[j]=v; hprev[j]=hp[j];
      if(b==0) x_dec[j]=v;
    }
  }
  __syncthreads();
  // all 64 attention rows per block (4 waves x 16 rows; identical per-row math)
  for(int rr=0;rr<16;rr++){
    int r=wave*16+rr;
    const float* wr = attn_W + (size_t)r*2048;
    float acc=0.0f;
    #pragma unroll
    for(int c4=0;c4<4;c4++){
      int m=c4*256+lane*4;
      acc += d4(*(const float4*)(wr+m),      *(const float4*)(&dec_in[m]));
      acc += d4(*(const float4*)(wr+1024+m), *(const float4*)(&hprev[m]));
    }
    acc=wred_sum(acc);
    if(lane==0) attw_raw[r]=acc+attn_b[r];
  }
  __syncthreads();
  // softmax (identical per block)
  if(tid<64){
    float v=attw_raw[tid];
    float mx=wred_max(v);
    float e=__expf(v-mx);
    float s=wred_sum(e);
    attw_s[tid]=e/s;
  }
  __syncthreads();
  // x_dec slice: block b covers j in [b*16, b*16+16)
  if(tid<16){
    int j=b*16+tid;
    float aA=0.0f, aS=0.0f;
    for(int k=0;k<ML;k++){
      float e=enc_outs[(size_t)k*1024+j];
      aA += attw_s[k]*e;
      aS += pc_s[k]*e;
    }
    x_dec[1024+j]=aS;
    x_dec[2048+j]=aA;
  }
}

// ---------------- decoder gates GEMV: 4096 x (3072 + 1024) ----------------
__global__ __launch_bounds__(256) void k_dec_gates(
  const float* __restrict__ Wih_d, const float* __restrict__ Whh_d,
  const float* __restrict__ bih_d, const float* __restrict__ bhh_d,
  float* __restrict__ ws, int t)
{
  __shared__ __align__(16) float x_lds[4096];
  const int tid=threadIdx.x;
  float* x_dec=ws+WS_X_DEC; float* h_dec=ws+WS_H_DEC; float* dg=ws+WS_DGATES;
  for(int j=tid;j<3072;j+=256) x_lds[j]=x_dec[j];
  {
    const float* hp=h_dec+((t+1)&1)*1024;   // h_{t-1}
    for(int j=tid;j<1024;j+=256) x_lds[3072+j]=hp[j];
  }
  __syncthreads();
  const int wave=tid>>6, lane=tid&63;
  for(int rr=0;rr<2;rr++){
    int r=blockIdx.x*8+wave*2+rr;
    const float* wr=Wih_d+(size_t)r*3072;
    float acc=0.0f;
    #pragma unroll
    for(int c4=0;c4<12;c4++){
      int m=c4*256+lane*4;
      acc += d4(*(const float4*)(wr+m), *(const float4*)(&x_lds[m]));
    }
    const float* hr=Whh_d+(size_t)r*1024;
    #pragma unroll
    for(int c4=0;c4<4;c4++){
      int m=c4*256+lane*4;
      acc += d4(*(const float4*)(hr+m), *(const float4*)(&x_lds[3072+m]));
    }
    acc=wred_sum(acc);
    if(lane==0) dg[r]=acc+bih_d[r]+bhh_d[r];
  }
}

// ---------------- decoder gen: redundant cell update + gen/copy GEMV + softmax partials ----------------
__global__ __launch_bounds__(256) void k_dec_gen(
  const float* __restrict__ gen_W, const float* __restrict__ gen_b,
  const float* __restrict__ amask,
  float* __restrict__ ws, float* __restrict__ out, int t)
{
  __shared__ __align__(16) float h_lds[1024];
  __shared__ float w_lm[4], w_sm[4], w_ky[4];
  __shared__ int w_ix[4];
  const int tid=threadIdx.x;
  float* dg=ws+WS_DGATES;
  float* c_dec=ws+WS_C_DEC; float* h_dec=ws+WS_H_DEC;
  float* logits=ws+WS_LOGITS; float* parts=ws+WS_PARTS;
  float* cenc=ws+WS_COPY_ENC;
  {
    const float* cp=c_dec+((t+1)&1)*1024;   // c_{t-1}
    float* cw=c_dec+(t&1)*1024;
    float* hw=h_dec+(t&1)*1024;
    for(int u=tid;u<1024;u+=256){
      float ig=dg[u], fg=dg[1024+u], gg=dg[2048+u], og=dg[3072+u];
      float c=sigm(fg)*cp[u]+sigm(ig)*tanhf(gg);
      float h=sigm(og)*tanhf(c);
      h_lds[u]=h;
      if(blockIdx.x==0){ cw[u]=c; hw[u]=h; out[(size_t)(t+1)*1024+u]=h; }  // states[t+1]
    }
  }
  __syncthreads();
  const int wave=tid>>6, lane=tid&63;
  const int b=blockIdx.x;
  const bool isGen=(b<500);
  const int rbase = isGen ? (b*64+wave*16) : (VOCAB+wave*16);
  float lv[16];
  #pragma unroll
  for(int rr=0;rr<16;rr++){
    const float* wr = isGen ? gen_W+(size_t)(rbase+rr)*1024
                            : cenc +(size_t)(rbase-VOCAB+rr)*1024;
    float acc=0.0f;
    #pragma unroll
    for(int c4=0;c4<4;c4++){
      int m=c4*256+lane*4;
      acc += d4(*(const float4*)(wr+m), *(const float4*)(&h_lds[m]));
    }
    acc=wred_sum(acc);
    lv[rr] = isGen ? acc+gen_b[rbase+rr] : acc;
  }
  if(lane==0){
    float lm=-INFINITY, ky=-INFINITY; int ix=0;
    #pragma unroll
    for(int rr=0;rr<16;rr++){
      int gi=rbase+rr;
      logits[gi]=lv[rr];
      lm=fmaxf(lm,lv[rr]);
      float mk=amask[gi];
      float kk = (mk>0.0f)? (lv[rr]+__logf(mk)) : -INFINITY;
      if(kk>ky){ ky=kk; ix=gi; }   // strict > keeps first index on ties
    }
    float sm=0.0f;
    #pragma unroll
    for(int rr=0;rr<16;rr++) sm += __expf(lv[rr]-lm);
    w_lm[wave]=lm; w_sm[wave]=sm; w_ky[wave]=ky; w_ix[wave]=ix;
  }
  __syncthreads();
  if(tid==0){
    float lm=w_lm[0], sm=w_sm[0], ky=w_ky[0]; int ix=w_ix[0];
    for(int w=1;w<4;w++){
      float blm=w_lm[w], bsm=w_sm[w];
      if(blm>lm){ sm=sm*__expf(lm-blm)+bsm; lm=blm; }
      else sm += bsm*__expf(blm-lm);
      if(w_ky[w]>ky || (w_ky[w]==ky && w_ix[w]<ix)){ ky=w_ky[w]; ix=w_ix[w]; }
    }
    float4 p; p.x=lm; p.y=sm; p.z=ky; p.w=__int_as_float(ix);
    *(float4*)(parts+(size_t)blockIdx.x*4)=p;
  }
}

extern "C" void kernel_launch(void* const* d_in, const int* in_sizes, int n_in,
                              void* d_out, int out_size, void* d_ws, size_t ws_size,
                              hipStream_t stream)
{
  const int*   xt     = (const int*)d_in[0];
  const float* amask  = (const float*)d_in[1];
  const float* emb    = (const float*)d_in[2];
  const float* Wih_f  = (const float*)d_in[3];
  const float* Whh_f  = (const float*)d_in[4];
  const float* bih_f  = (const float*)d_in[5];
  const float* bhh_f  = (const float*)d_in[6];
  const float* Wih_b  = (const float*)d_in[7];
  const float* Whh_b  = (const float*)d_in[8];
  const float* bih_b  = (const float*)d_in[9];
  const float* bhh_b  = (const float*)d_in[10];
  const float* Wih_d  = (const float*)d_in[11];
  const float* Whh_d  = (const float*)d_in[12];
  const float* bih_d  = (const float*)d_in[13];
  const float* bhh_d  = (const float*)d_in[14];
  const float* attn_W = (const float*)d_in[15];
  const float* attn_b = (const float*)d_in[16];
  const float* gen_W  = (const float*)d_in[17];
  const float* gen_b  = (const float*)d_in[18];
  const float* copy_W = (const float*)d_in[19];
  const float* copy_b = (const float*)d_in[20];
  float* out=(float*)d_out;
  float* ws =(float*)d_ws;

  const bool big = ws_size >= (size_t)WS_PREG_END*sizeof(float);
  if(big){
    k_enc_pre<<<512,256,0,stream>>>(xt,emb,Wih_f,bih_f,bhh_f,Wih_b,bih_b,bhh_b,ws);
    for(int t=0;t<L;t++)
      k_enc_rec<<<512,256,0,stream>>>(Whh_f,Whh_b,ws,t);
  } else {
    for(int t=0;t<L;t++)
      k_enc_step<<<512,256,0,stream>>>(xt,emb,Wih_f,Whh_f,bih_f,bhh_f,Wih_b,Whh_b,bih_b,bhh_b,ws,t);
  }
  k_copy_final<<<256,256,0,stream>>>(emb,copy_W,copy_b,ws,out);

  k_dec_gates<<<512,256,0,stream>>>(Wih_d,Whh_d,bih_d,bhh_d,ws,0);
  k_dec_gen  <<<501,256,0,stream>>>(gen_W,gen_b,amask,ws,out,0);
  for(int t=1;t<ML;t++){
    k_attn_prep<<<64,256,0,stream>>>(xt,amask,emb,attn_W,attn_b,ws,out,t,0);
    k_dec_gates<<<512,256,0,stream>>>(Wih_d,Whh_d,bih_d,bhh_d,ws,t);
    k_dec_gen  <<<501,256,0,stream>>>(gen_W,gen_b,amask,ws,out,t);
  }
  k_attn_prep<<<1,256,0,stream>>>(xt,amask,emb,attn_W,attn_b,ws,out,ML,1);
}

// Round 7
// 3539.984 us; speedup vs baseline: 1.3158x; 1.3158x over previous
//
#include <hip/hip_runtime.h>
#include <math.h>

#define L 50
#define ML 64
#define VOCAB 32000
#define EMBED 1024
#define HID 1024
#define HH 512
#define TOT (VOCAB+ML)
#define NPART 501

// workspace layout (float offsets)
#define WS_ENC_GATES 0        // [2][4096]
#define WS_C_ENC     8192     // [2][1024]
#define WS_ENC_OUTS  10240    // [64][1024]
#define WS_COPY_ENC  75776    // [64][1024]
#define WS_H_DEC     141312   // [2][1024]
#define WS_C_DEC     143360   // [2][1024]
#define WS_X_DEC     145408   // [3072]
#define WS_DGATES    148480   // [4096]
#define WS_LOGITS    152576   // [32064]
#define WS_PARTS     184640   // [501*4] {lmax,sumexp,bestkey,bestidx}
#define WS_ATTW      186688   // [64] softmaxed attention weights
#define WS_PC        186752   // [64] selective-read weights
#define WS_G         186816   // [8192][64]: rows 0..4095 = G_sel, 4096..8191 = G_att
#define WS_G_END     (186816+8192*64)

__device__ __forceinline__ float wred_sum(float v){
  #pragma unroll
  for(int o=32;o;o>>=1) v += __shfl_xor(v,o,64);
  return v;
}
__device__ __forceinline__ float wred_max(float v){
  #pragma unroll
  for(int o=32;o;o>>=1) v = fmaxf(v,__shfl_xor(v,o,64));
  return v;
}
__device__ __forceinline__ float sigm(float x){ return 1.0f/(1.0f+__expf(-x)); }
__device__ __forceinline__ float d4(float4 a, float4 b){ return a.x*b.x + a.y*b.y + a.z*b.z + a.w*b.w; }

// ================= encoder step (round-4 proven) =================
__global__ __launch_bounds__(256) void k_enc_step(
  const int* __restrict__ xt, const float* __restrict__ emb,
  const float* __restrict__ Wih_f, const float* __restrict__ Whh_f,
  const float* __restrict__ bih_f, const float* __restrict__ bhh_f,
  const float* __restrict__ Wih_b, const float* __restrict__ Whh_b,
  const float* __restrict__ bih_b, const float* __restrict__ bhh_b,
  float* __restrict__ ws, int t)
{
  __shared__ __align__(16) float h_lds[1024];
  __shared__ __align__(16) float xe[1024];
  const int tid = threadIdx.x;
  float* gates   = ws + WS_ENC_GATES;
  float* c_enc   = ws + WS_C_ENC;
  float* enc_outs= ws + WS_ENC_OUTS;
  {
    const int tok = xt[t];
    const float* er = emb + (size_t)tok*EMBED;
    for(int j=tid;j<1024;j+=256) xe[j]=er[j];
  }
  if(t>0){
    const float* gp = gates + ((t-1)&1)*4096;
    const float* cp = c_enc + (t&1)*1024;
    float* cw = c_enc + ((t-1)&1)*1024;
    for(int u=tid;u<1024;u+=256){
      int base=(u<512)?0:2048, uu=(u<512)?u:(u-512);
      float ig=gp[base+uu], fg=gp[base+512+uu], gg=gp[base+1024+uu], og=gp[base+1536+uu];
      float cprev=(t==1)?0.0f:cp[u];
      float c=sigm(fg)*cprev+sigm(ig)*tanhf(gg);
      float h=sigm(og)*tanhf(c);
      h_lds[u]=h;
      if(blockIdx.x==0){ cw[u]=c; enc_outs[(size_t)(t-1)*1024+u]=h; }
    }
  }
  __syncthreads();
  float* gw = gates + (t&1)*4096;
  const int wave=tid>>6, lane=tid&63;
  for(int rr=0;rr<2;rr++){
    int r=blockIdx.x*8+wave*2+rr;
    bool isF=(r<2048); int rl=isF?r:(r-2048);
    const float* Wih=isF?Wih_f:Wih_b;
    const float* Whh=isF?Whh_f:Whh_b;
    float bias=isF?(bih_f[rl]+bhh_f[rl]):(bih_b[rl]+bhh_b[rl]);
    const float* wr=Wih+(size_t)rl*EMBED;
    float acc=0.0f;
    #pragma unroll
    for(int c4=0;c4<4;c4++){
      int m=c4*256+lane*4;
      acc += d4(*(const float4*)(wr+m), *(const float4*)(&xe[m]));
    }
    if(t>0){
      const float* hr=Whh+(size_t)rl*HH;
      const float* hs=&h_lds[isF?0:512];
      #pragma unroll
      for(int c2=0;c2<2;c2++){
        int m=c2*256+lane*4;
        acc += d4(*(const float4*)(hr+m), *(const float4*)(&hs[m]));
      }
    }
    acc=wred_sum(acc);
    if(lane==0) gw[r]=acc+bias;
  }
}

// ================= k_copy_final (round-5 proven) =================
__global__ __launch_bounds__(256) void k_copy_final(
  const float* __restrict__ emb,
  const float* __restrict__ copy_W, const float* __restrict__ copy_b,
  float* __restrict__ ws, float* __restrict__ out)
{
  __shared__ __align__(16) float hf[1024];
  const int tid=threadIdx.x, b=blockIdx.x, wave=tid>>6, lane=tid&63;
  float* gates = ws + WS_ENC_GATES;
  float* c_enc = ws + WS_C_ENC;
  float* enc_outs = ws + WS_ENC_OUTS;
  float* cenc = ws + WS_COPY_ENC;
  float* h_dec = ws + WS_H_DEC;
  float* c_dec = ws + WS_C_DEC;
  float* x_dec = ws + WS_X_DEC;
  {
    const float* gp = gates + ((L-1)&1)*4096;
    const float* cp = c_enc + ((L-2)&1)*1024;
    for(int u=tid;u<1024;u+=256){
      int base=(u<512)?0:2048, uu=(u<512)?u:(u-512);
      float ig=gp[base+uu], fg=gp[base+512+uu], gg=gp[base+1024+uu], og=gp[base+1536+uu];
      float c=sigm(fg)*cp[u]+sigm(ig)*tanhf(gg);
      float h=sigm(og)*tanhf(c);
      hf[u]=h;
      if(b==0){
        enc_outs[(size_t)(L-1)*1024+u]=h;
        h_dec[1024+u]=h;
        c_dec[1024+u]=c;
        out[u]=h;
      }
    }
    if(b==1) for(int j=tid;j<(ML-L)*1024;j+=256) enc_outs[(size_t)L*1024+j]=0.0f;
    if(b==2) for(int j=tid;j<1024;j+=256){
      x_dec[j]=emb[j];
      x_dec[1024+j]=0.0f;
      x_dec[2048+j]=0.0f;
    }
  }
  __syncthreads();
  int j = b*4 + wave;
  const float* wr = copy_W + (size_t)j*1024;
  float4 w0=*(const float4*)(wr+0*256+lane*4);
  float4 w1=*(const float4*)(wr+1*256+lane*4);
  float4 w2=*(const float4*)(wr+2*256+lane*4);
  float4 w3=*(const float4*)(wr+3*256+lane*4);
  float bj = copy_b[j];
  for(int k=0;k<L-1;k++){
    const float* er = enc_outs + (size_t)k*1024;
    float acc = d4(w0,*(const float4*)(er+0*256+lane*4))
              + d4(w1,*(const float4*)(er+1*256+lane*4))
              + d4(w2,*(const float4*)(er+2*256+lane*4))
              + d4(w3,*(const float4*)(er+3*256+lane*4));
    acc = wred_sum(acc);
    if(lane==0) cenc[(size_t)k*1024+j]=tanhf(acc+bj);
  }
  {
    float acc = d4(w0,*(const float4*)(&hf[0*256+lane*4]))
              + d4(w1,*(const float4*)(&hf[1*256+lane*4]))
              + d4(w2,*(const float4*)(&hf[2*256+lane*4]))
              + d4(w3,*(const float4*)(&hf[3*256+lane*4]));
    acc = wred_sum(acc);
    if(lane==0) cenc[(size_t)(L-1)*1024+j]=tanhf(acc+bj);
  }
  if(lane==0){
    float z=tanhf(0.0f+bj);
    for(int k=L;k<ML;k++) cenc[(size_t)k*1024+j]=z;
  }
}

// ================= k_gmat: G_sel/G_att = W_sel/W_att @ enc_outs^T (one-time) =================
__global__ __launch_bounds__(256) void k_gmat(const float* __restrict__ Wih_d, float* __restrict__ ws)
{
  __shared__ __align__(16) float elds[16*1024];   // 64 KB
  const int tid=threadIdx.x, wave=tid>>6, lane=tid&63;
  const float* enc = ws + WS_ENC_OUTS;
  float* G = ws + WS_G;
  float4 w[4][4];
  int rg[4];
  #pragma unroll
  for(int q=0;q<4;q++){
    int r = blockIdx.x*16 + wave*4 + q;     // 0..8191
    rg[q]=r;
    const float* W = (r<4096) ? (Wih_d + (size_t)r*3072 + 1024)
                              : (Wih_d + (size_t)(r-4096)*3072 + 2048);
    #pragma unroll
    for(int c4=0;c4<4;c4++) w[q][c4]=*(const float4*)(W + c4*256 + lane*4);
  }
  for(int chunk=0;chunk<4;chunk++){
    __syncthreads();
    for(int idx=tid; idx<16*1024; idx+=256) elds[idx]=enc[(size_t)chunk*16*1024+idx];
    __syncthreads();
    for(int k=0;k<16;k++){
      #pragma unroll
      for(int q=0;q<4;q++){
        float acc=0.0f;
        #pragma unroll
        for(int c4=0;c4<4;c4++)
          acc += d4(w[q][c4], *(const float4*)(&elds[k*1024 + c4*256 + lane*4]));
        acc=wred_sum(acc);
        if(lane==0) G[(size_t)rg[q]*64 + chunk*16 + k]=acc;
      }
    }
  }
}

// ================= k_fin: finalize step t-1 + pc + attn logits + softmax (1 block x 1024) =================
__global__ __launch_bounds__(1024) void k_fin(
  const int* __restrict__ xt, const float* __restrict__ amask,
  const float* __restrict__ emb,
  const float* __restrict__ attn_W, const float* __restrict__ attn_b,
  float* __restrict__ ws, float* __restrict__ out, int t, int fin_only)
{
  __shared__ __align__(16) float dec_in[1024];
  __shared__ __align__(16) float hprev[1024];
  __shared__ float r_lm[1024], r_sm[1024], r_ky[1024];
  __shared__ int r_ix[1024];
  __shared__ float attw_raw[64];
  __shared__ float s_lmax, s_Z;
  __shared__ int s_act;
  const int tid=threadIdx.x, wave=tid>>6, lane=tid&63;
  float* h_dec=ws+WS_H_DEC; float* x_dec=ws+WS_X_DEC;
  float* logits=ws+WS_LOGITS; float* parts=ws+WS_PARTS;
  float* aww=ws+WS_ATTW; float* pcw=ws+WS_PC;

  if(t==0){
    for(int j=tid;j<1024;j+=1024) x_dec[j]=emb[j];   // sos
    if(tid<64){ aww[tid]=0.0f; pcw[tid]=0.0f; }      // attentive/selective = 0 at t=0
    return;
  }
  // ---- finalize step t-1 (FINITE sentinel -1e30f: -INF padding NaN'd via 0*expf(-INF-(-INF))) ----
  {
    float lm=-1e30f, sm=0.0f, ky=-1e30f; int ix=0x7fffffff;
    if(tid<NPART){
      const float4 p = *(const float4*)(parts+(size_t)tid*4);
      lm=p.x; sm=p.y; ky=p.z; ix=__float_as_int(p.w);
    }
    r_lm[tid]=lm; r_sm[tid]=sm; r_ky[tid]=ky; r_ix[tid]=ix;
    __syncthreads();
    for(int s=512;s;s>>=1){
      if(tid<s){
        float blm=r_lm[tid+s], bsm=r_sm[tid+s];
        float alm=r_lm[tid], a_sm=r_sm[tid];
        if(blm>alm){ r_sm[tid]=a_sm*__expf(alm-blm)+bsm; r_lm[tid]=blm; }
        else r_sm[tid]=a_sm+bsm*__expf(blm-alm);
        float bky=r_ky[tid+s]; int bix=r_ix[tid+s];
        if(bky>r_ky[tid] || (bky==r_ky[tid] && bix<r_ix[tid])){ r_ky[tid]=bky; r_ix[tid]=bix; }
      }
      __syncthreads();
    }
    if(tid==0){
      float lmax=r_lm[0], Z=r_sm[0];
      int aidx=(r_ky[0]<=-1e29f)?0:r_ix[0];
      bool isv=(aidx<VOCAB);
      int kcl=aidx-VOCAB; kcl=kcl<0?0:(kcl>(L-1)?(L-1):kcl);
      int sp=xt[kcl];
      int action=isv?aidx:sp;
      float prob=amask[aidx]*__expf(logits[aidx]-lmax)/Z;
      if(!isv){
        int a2=action<0?0:(action>(VOCAB-1)?(VOCAB-1):action);
        prob += amask[a2]*__expf(logits[a2]-lmax)/Z;
      }
      out[65*1024 + (t-1)] = prob;
      out[65*1024 + 64 + (t-1)] = (float)action;
      s_lmax=lmax; s_Z=Z; s_act=action;
    }
  }
  __syncthreads();
  if(fin_only) return;

  const int action=s_act;
  // pc
  if(tid<64){
    int k=tid;
    float v=__expf(logits[VOCAB+k]-s_lmax)/s_Z;
    int sp=(k<L)? xt[k] : -1;
    float m=(k>=1 && k<(L-1) && sp!=action)?1.0f:0.0f;
    float pv=v*m;
    float s=wred_sum(pv);
    pcw[k]=(s>0.0f)? pv/s : pv;
  }
  // dec_in + hprev
  {
    int row = action<0 ? action+VOCAB : action;
    const float* er = emb + (size_t)row*EMBED;
    const float* hp = h_dec + ((t-1)&1)*1024;
    for(int j=tid;j<1024;j+=1024){
      float v=er[j];
      dec_in[j]=v; hprev[j]=hp[j];
      x_dec[j]=v;
    }
  }
  __syncthreads();
  // 64 attention rows: 16 waves x 4 rows (identical per-row math to round 4)
  for(int rr=0;rr<4;rr++){
    int r=wave*4+rr;
    const float* wr = attn_W + (size_t)r*2048;
    float acc=0.0f;
    #pragma unroll
    for(int c4=0;c4<4;c4++){
      int m=c4*256+lane*4;
      acc += d4(*(const float4*)(wr+m),      *(const float4*)(&dec_in[m]));
      acc += d4(*(const float4*)(wr+1024+m), *(const float4*)(&hprev[m]));
    }
    acc=wred_sum(acc);
    if(lane==0) attw_raw[r]=acc+attn_b[r];
  }
  __syncthreads();
  if(tid<64){
    float v=attw_raw[tid];
    float mx=wred_max(v);
    float e=__expf(v-mx);
    float s=wred_sum(e);
    aww[tid]=e/s;
  }
}

// ================= k_dec_gates2: gates = W_dec.dec_in + G_sel.pc + G_att.attw + Whh_d.h + bias =================
__global__ __launch_bounds__(256) void k_dec_gates2(
  const float* __restrict__ Wih_d, const float* __restrict__ Whh_d,
  const float* __restrict__ bih_d, const float* __restrict__ bhh_d,
  float* __restrict__ ws, int t)
{
  __shared__ __align__(16) float di[1024];
  __shared__ __align__(16) float hh[1024];
  __shared__ float pcs[64], aws[64];
  const int tid=threadIdx.x;
  float* x_dec=ws+WS_X_DEC; float* h_dec=ws+WS_H_DEC; float* dg=ws+WS_DGATES;
  const float* G=ws+WS_G;
  for(int j=tid;j<1024;j+=256) di[j]=x_dec[j];
  {
    const float* hp=h_dec+((t+1)&1)*1024;   // h_{t-1}
    for(int j=tid;j<1024;j+=256) hh[j]=hp[j];
  }
  if(tid<64){ pcs[tid]=(ws+WS_PC)[tid]; aws[tid]=(ws+WS_ATTW)[tid]; }
  __syncthreads();
  const int wave=tid>>6, lane=tid&63;
  for(int rr=0;rr<2;rr++){
    int r=blockIdx.x*8+wave*2+rr;
    const float* wd=Wih_d+(size_t)r*3072;       // dec_in part (cols 0..1023)
    float acc=0.0f;
    #pragma unroll
    for(int c4=0;c4<4;c4++){
      int m=c4*256+lane*4;
      acc += d4(*(const float4*)(wd+m), *(const float4*)(&di[m]));
    }
    const float* hr=Whh_d+(size_t)r*1024;
    #pragma unroll
    for(int c4=0;c4<4;c4++){
      int m=c4*256+lane*4;
      acc += d4(*(const float4*)(hr+m), *(const float4*)(&hh[m]));
    }
    acc += G[(size_t)r*64+lane]*pcs[lane];
    acc += G[(size_t)(4096+r)*64+lane]*aws[lane];
    acc=wred_sum(acc);
    if(lane==0) dg[r]=acc+bih_d[r]+bhh_d[r];
  }
}

// ================= fallback (round-4) kernels =================
__global__ __launch_bounds__(256) void k_dec_init(const float* __restrict__ emb, float* __restrict__ ws)
{
  float* x_dec=ws+WS_X_DEC;
  for(int j=threadIdx.x;j<1024;j+=256){
    x_dec[j]=emb[j];
    x_dec[1024+j]=0.0f;
    x_dec[2048+j]=0.0f;
  }
}

__global__ __launch_bounds__(256) void k_attn(
  const int* __restrict__ xt, const float* __restrict__ amask,
  const float* __restrict__ emb,
  const float* __restrict__ attn_W, const float* __restrict__ attn_b,
  float* __restrict__ ws, float* __restrict__ out, int t, int fin_only)
{
  __shared__ __align__(16) float dec_in[1024];
  __shared__ __align__(16) float hprev[1024];
  __shared__ float r_lm[256], r_sm[256], r_ky[256];
  __shared__ int r_ix[256];
  __shared__ float s_lmax, s_Z;
  __shared__ int s_act;
  const int tid=threadIdx.x;
  float* h_dec=ws+WS_H_DEC; float* x_dec=ws+WS_X_DEC;
  float* logits=ws+WS_LOGITS; float* parts=ws+WS_PARTS;
  float* attw_raw=ws+WS_ATTW; float* pcw=ws+WS_PC;
  {
    float lm=-INFINITY, sm=0.0f, ky=-INFINITY; int ix=0x7fffffff;
    for(int i=tid;i<NPART;i+=256){
      const float4 p = *(const float4*)(parts+(size_t)i*4);
      float plm=p.x, psm=p.y, pky=p.z; int pix=__float_as_int(p.w);
      if(plm>lm){ sm = sm*__expf(lm-plm)+psm; lm=plm; }
      else sm += psm*__expf(plm-lm);
      if(pky>ky || (pky==ky && pix<ix)){ ky=pky; ix=pix; }
    }
    r_lm[tid]=lm; r_sm[tid]=sm; r_ky[tid]=ky; r_ix[tid]=ix;
    __syncthreads();
    for(int s=128;s;s>>=1){
      if(tid<s){
        float blm=r_lm[tid+s], bsm=r_sm[tid+s];
        float alm=r_lm[tid], a_sm=r_sm[tid];
        if(blm>alm){ r_sm[tid]=a_sm*__expf(alm-blm)+bsm; r_lm[tid]=blm; }
        else r_sm[tid]=a_sm+bsm*__expf(blm-alm);
        float bky=r_ky[tid+s]; int bix=r_ix[tid+s];
        if(bky>r_ky[tid] || (bky==r_ky[tid] && bix<r_ix[tid])){ r_ky[tid]=bky; r_ix[tid]=bix; }
      }
      __syncthreads();
    }
    if(tid==0){
      float lmax=r_lm[0]; float Z=r_sm[0];
      float bky=r_ky[0];
      int aidx = (bky==-INFINITY)?0:r_ix[0];
      bool isv = aidx<VOCAB;
      int kcl = aidx-VOCAB; kcl = kcl<0?0:(kcl>(L-1)?(L-1):kcl);
      int sp = xt[kcl];
      int action = isv? aidx : sp;
      if(blockIdx.x==0){
        float prob = amask[aidx]*__expf(logits[aidx]-lmax)/Z;
        if(!isv){
          int a2 = action<0?0:(action>(VOCAB-1)?(VOCAB-1):action);
          prob += amask[a2]*__expf(logits[a2]-lmax)/Z;
        }
        out[65*1024 + (t-1)] = prob;
        out[65*1024 + 64 + (t-1)] = (float)action;
      }
      s_lmax=lmax; s_Z=Z; s_act=action;
    }
  }
  __syncthreads();
  if(fin_only) return;
  const int action = s_act;
  if(blockIdx.x==0 && tid<64){
    int k=tid;
    float v=__expf(logits[VOCAB+k]-s_lmax)/s_Z;
    int sp=(k<L)? xt[k] : -1;
    float m=(k>=1 && k<(L-1) && sp!=action)?1.0f:0.0f;
    float pv=v*m;
    float s=wred_sum(pv);
    pcw[k]=(s>0.0f)? pv/s : pv;
  }
  {
    int row = action<0 ? action+VOCAB : action;
    const float* er = emb + (size_t)row*EMBED;
    const float* hp = h_dec + ((t-1)&1)*1024;
    for(int j=tid;j<1024;j+=256){
      float v=er[j];
      dec_in[j]=v; hprev[j]=hp[j];
      if(blockIdx.x==0) x_dec[j]=v;
    }
  }
  __syncthreads();
  if(tid<64){
    const int lane=tid;
    const float* wr = attn_W + (size_t)blockIdx.x*2048;
    float acc=0.0f;
    #pragma unroll
    for(int c4=0;c4<4;c4++){
      int m=c4*256+lane*4;
      acc += d4(*(const float4*)(wr+m),      *(const float4*)(&dec_in[m]));
      acc += d4(*(const float4*)(wr+1024+m), *(const float4*)(&hprev[m]));
    }
    acc=wred_sum(acc);
    if(lane==0) attw_raw[blockIdx.x]=acc+attn_b[blockIdx.x];
  }
}

__global__ __launch_bounds__(256) void k_prep(float* __restrict__ ws)
{
  __shared__ float attw_s[64], pc_s[64];
  const int tid=threadIdx.x;
  float* enc_outs=ws+WS_ENC_OUTS; float* x_dec=ws+WS_X_DEC;
  float* attw_raw=ws+WS_ATTW; float* pcw=ws+WS_PC;
  if(tid<64){
    float v=attw_raw[tid];
    float mx=wred_max(v);
    float e=__expf(v-mx);
    float s=wred_sum(e);
    attw_s[tid]=e/s;
    pc_s[tid]=pcw[tid];
  }
  __syncthreads();
  int j=blockIdx.x*256+tid;
  float aA=0.0f, aS=0.0f;
  for(int k=0;k<ML;k++){
    float e=enc_outs[(size_t)k*1024+j];
    aA += attw_s[k]*e;
    aS += pc_s[k]*e;
  }
  x_dec[1024+j]=aS;
  x_dec[2048+j]=aA;
}

__global__ __launch_bounds__(256) void k_dec_gates(
  const float* __restrict__ Wih_d, const float* __restrict__ Whh_d,
  const float* __restrict__ bih_d, const float* __restrict__ bhh_d,
  float* __restrict__ ws, int t)
{
  __shared__ __align__(16) float x_lds[4096];
  const int tid=threadIdx.x;
  float* x_dec=ws+WS_X_DEC; float* h_dec=ws+WS_H_DEC; float* dg=ws+WS_DGATES;
  for(int j=tid;j<3072;j+=256) x_lds[j]=x_dec[j];
  {
    const float* hp=h_dec+((t+1)&1)*1024;
    for(int j=tid;j<1024;j+=256) x_lds[3072+j]=hp[j];
  }
  __syncthreads();
  const int wave=tid>>6, lane=tid&63;
  for(int rr=0;rr<2;rr++){
    int r=blockIdx.x*8+wave*2+rr;
    const float* wr=Wih_d+(size_t)r*3072;
    float acc=0.0f;
    #pragma unroll
    for(int c4=0;c4<12;c4++){
      int m=c4*256+lane*4;
      acc += d4(*(const float4*)(wr+m), *(const float4*)(&x_lds[m]));
    }
    const float* hr=Whh_d+(size_t)r*1024;
    #pragma unroll
    for(int c4=0;c4<4;c4++){
      int m=c4*256+lane*4;
      acc += d4(*(const float4*)(hr+m), *(const float4*)(&x_lds[3072+m]));
    }
    acc=wred_sum(acc);
    if(lane==0) dg[r]=acc+bih_d[r]+bhh_d[r];
  }
}

// ================= decoder gen (unchanged, both paths) =================
__global__ __launch_bounds__(256) void k_dec_gen(
  const float* __restrict__ gen_W, const float* __restrict__ gen_b,
  const float* __restrict__ amask,
  float* __restrict__ ws, float* __restrict__ out, int t)
{
  __shared__ __align__(16) float h_lds[1024];
  __shared__ float w_lm[4], w_sm[4], w_ky[4];
  __shared__ int w_ix[4];
  const int tid=threadIdx.x;
  float* dg=ws+WS_DGATES;
  float* c_dec=ws+WS_C_DEC; float* h_dec=ws+WS_H_DEC;
  float* logits=ws+WS_LOGITS; float* parts=ws+WS_PARTS;
  float* cenc=ws+WS_COPY_ENC;
  {
    const float* cp=c_dec+((t+1)&1)*1024;
    float* cw=c_dec+(t&1)*1024;
    float* hw=h_dec+(t&1)*1024;
    for(int u=tid;u<1024;u+=256){
      float ig=dg[u], fg=dg[1024+u], gg=dg[2048+u], og=dg[3072+u];
      float c=sigm(fg)*cp[u]+sigm(ig)*tanhf(gg);
      float h=sigm(og)*tanhf(c);
      h_lds[u]=h;
      if(blockIdx.x==0){ cw[u]=c; hw[u]=h; out[(size_t)(t+1)*1024+u]=h; }
    }
  }
  __syncthreads();
  const int wave=tid>>6, lane=tid&63;
  const int b=blockIdx.x;
  const bool isGen=(b<500);
  const int rbase = isGen ? (b*64+wave*16) : (VOCAB+wave*16);
  float lv[16];
  #pragma unroll
  for(int rr=0;rr<16;rr++){
    const float* wr = isGen ? gen_W+(size_t)(rbase+rr)*1024
                            : cenc +(size_t)(rbase-VOCAB+rr)*1024;
    float acc=0.0f;
    #pragma unroll
    for(int c4=0;c4<4;c4++){
      int m=c4*256+lane*4;
      acc += d4(*(const float4*)(wr+m), *(const float4*)(&h_lds[m]));
    }
    acc=wred_sum(acc);
    lv[rr] = isGen ? acc+gen_b[rbase+rr] : acc;
  }
  if(lane==0){
    float lm=-INFINITY, ky=-INFINITY; int ix=0;
    #pragma unroll
    for(int rr=0;rr<16;rr++){
      int gi=rbase+rr;
      logits[gi]=lv[rr];
      lm=fmaxf(lm,lv[rr]);
      float mk=amask[gi];
      float kk = (mk>0.0f)? (lv[rr]+__logf(mk)) : -INFINITY;
      if(kk>ky){ ky=kk; ix=gi; }
    }
    float sm=0.0f;
    #pragma unroll
    for(int rr=0;rr<16;rr++) sm += __expf(lv[rr]-lm);
    w_lm[wave]=lm; w_sm[wave]=sm; w_ky[wave]=ky; w_ix[wave]=ix;
  }
  __syncthreads();
  if(tid==0){
    float lm=w_lm[0], sm=w_sm[0], ky=w_ky[0]; int ix=w_ix[0];
    for(int w=1;w<4;w++){
      float blm=w_lm[w], bsm=w_sm[w];
      if(blm>lm){ sm=sm*__expf(lm-blm)+bsm; lm=blm; }
      else sm += bsm*__expf(blm-lm);
      if(w_ky[w]>ky || (w_ky[w]==ky && w_ix[w]<ix)){ ky=w_ky[w]; ix=w_ix[w]; }
    }
    float4 p; p.x=lm; p.y=sm; p.z=ky; p.w=__int_as_float(ix);
    *(float4*)(parts+(size_t)blockIdx.x*4)=p;
  }
}

extern "C" void kernel_launch(void* const* d_in, const int* in_sizes, int n_in,
                              void* d_out, int out_size, void* d_ws, size_t ws_size,
                              hipStream_t stream)
{
  const int*   xt     = (const int*)d_in[0];
  const float* amask  = (const float*)d_in[1];
  const float* emb    = (const float*)d_in[2];
  const float* Wih_f  = (const float*)d_in[3];
  const float* Whh_f  = (const float*)d_in[4];
  const float* bih_f  = (const float*)d_in[5];
  const float* bhh_f  = (const float*)d_in[6];
  const float* Wih_b  = (const float*)d_in[7];
  const float* Whh_b  = (const float*)d_in[8];
  const float* bih_b  = (const float*)d_in[9];
  const float* bhh_b  = (const float*)d_in[10];
  const float* Wih_d  = (const float*)d_in[11];
  const float* Whh_d  = (const float*)d_in[12];
  const float* bih_d  = (const float*)d_in[13];
  const float* bhh_d  = (const float*)d_in[14];
  const float* attn_W = (const float*)d_in[15];
  const float* attn_b = (const float*)d_in[16];
  const float* gen_W  = (const float*)d_in[17];
  const float* gen_b  = (const float*)d_in[18];
  const float* copy_W = (const float*)d_in[19];
  const float* copy_b = (const float*)d_in[20];
  float* out=(float*)d_out;
  float* ws =(float*)d_ws;

  for(int t=0;t<L;t++)
    k_enc_step<<<512,256,0,stream>>>(xt,emb,Wih_f,Whh_f,bih_f,bhh_f,Wih_b,Whh_b,bih_b,bhh_b,ws,t);
  k_copy_final<<<256,256,0,stream>>>(emb,copy_W,copy_b,ws,out);

  const bool big = ws_size >= (size_t)WS_G_END*sizeof(float);
  if(big){
    k_gmat<<<512,256,0,stream>>>(Wih_d,ws);
    for(int t=0;t<ML;t++){
      k_fin       <<<1,1024,0,stream>>>(xt,amask,emb,attn_W,attn_b,ws,out,t,0);
      k_dec_gates2<<<512,256,0,stream>>>(Wih_d,Whh_d,bih_d,bhh_d,ws,t);
      k_dec_gen   <<<501,256,0,stream>>>(gen_W,gen_b,amask,ws,out,t);
    }
    k_fin<<<1,1024,0,stream>>>(xt,amask,emb,attn_W,attn_b,ws,out,ML,1);
  } else {
    k_dec_init<<<1,256,0,stream>>>(emb,ws);
    k_dec_gates<<<512,256,0,stream>>>(Wih_d,Whh_d,bih_d,bhh_d,ws,0);
    k_dec_gen  <<<501,256,0,stream>>>(gen_W,gen_b,amask,ws,out,0);
    for(int t=1;t<ML;t++){
      k_attn     <<<64,256,0,stream>>>(xt,amask,emb,attn_W,attn_b,ws,out,t,0);
      k_prep     <<<4,256,0,stream>>>(ws);
      k_dec_gates<<<512,256,0,stream>>>(Wih_d,Whh_d,bih_d,bhh_d,ws,t);
      k_dec_gen  <<<501,256,0,stream>>>(gen_W,gen_b,amask,ws,out,t);
    }
    k_attn<<<1,256,0,stream>>>(xt,amask,emb,attn_W,attn_b,ws,out,ML,1);
  }
}

// Round 8
// 3099.054 us; speedup vs baseline: 1.5031x; 1.1423x over previous
//
#include <hip/hip_runtime.h>
#include <math.h>

#define L 50
#define ML 64
#define VOCAB 32000
#define EMBED 1024
#define HID 1024
#define HH 512
#define TOT (VOCAB+ML)
#define NPART 501

// workspace layout (float offsets)
#define WS_ENC_GATES 0        // [2][4096]
#define WS_C_ENC     8192     // [2][1024]
#define WS_ENC_OUTS  10240    // [64][1024]
#define WS_COPY_ENC  75776    // [64][1024]
#define WS_H_DEC     141312   // [2][1024]
#define WS_C_DEC     143360   // [2][1024]
#define WS_X_DEC     145408   // [3072]
#define WS_DGATES    148480   // [4096]
#define WS_LOGITS    152576   // [32064]
#define WS_PARTS     184640   // [501*4] {lmax,sumexp,bestkey,bestidx}
#define WS_ATTW      186688   // [64] RAW attention logits
#define WS_PC        186752   // [64] selective-read weights
#define WS_ACT       186816   // [1] action (int)
#define WS_G         186880   // [8192][64]: rows 0..4095 = G_sel, 4096..8191 = G_att
#define WS_G_END     (186880+8192*64)          // 711168
#define WS_PREG      711168   // [50][4096] encoder input-side pregates
#define WS_END       (711168+50*4096)          // 915968

__device__ __forceinline__ float wred_sum(float v){
  #pragma unroll
  for(int o=32;o;o>>=1) v += __shfl_xor(v,o,64);
  return v;
}
__device__ __forceinline__ float wred_max(float v){
  #pragma unroll
  for(int o=32;o;o>>=1) v = fmaxf(v,__shfl_xor(v,o,64));
  return v;
}
__device__ __forceinline__ float sigm(float x){ return 1.0f/(1.0f+__expf(-x)); }
__device__ __forceinline__ float d4(float4 a, float4 b){ return a.x*b.x + a.y*b.y + a.z*b.z + a.w*b.w; }

// ================= encoder pregates, barrier-free: pg[t][r] = Wih.xemb_t + bias =================
__global__ __launch_bounds__(256) void k_enc_pre2(
  const int* __restrict__ xt, const float* __restrict__ emb,
  const float* __restrict__ Wih_f, const float* __restrict__ bih_f, const float* __restrict__ bhh_f,
  const float* __restrict__ Wih_b, const float* __restrict__ bih_b, const float* __restrict__ bhh_b,
  float* __restrict__ ws)
{
  __shared__ int toks[L];
  const int tid=threadIdx.x, b=blockIdx.x, wave=tid>>6, lane=tid&63;
  float* pg = ws + WS_PREG;
  if(tid<L) toks[tid]=xt[tid];
  float4 wih[2][4]; float bias[2];
  #pragma unroll
  for(int rr=0;rr<2;rr++){
    int r=b*8+wave*2+rr; bool isF=(r<2048); int rl=isF?r:(r-2048);
    const float* wp=(isF?Wih_f:Wih_b)+(size_t)rl*EMBED;
    #pragma unroll
    for(int c4=0;c4<4;c4++) wih[rr][c4]=*(const float4*)(wp+c4*256+lane*4);
    bias[rr]= isF?(bih_f[rl]+bhh_f[rl]):(bih_b[rl]+bhh_b[rl]);
  }
  __syncthreads();
  for(int t=0;t<L;t++){
    const float* er = emb + (size_t)toks[t]*EMBED;
    #pragma unroll
    for(int rr=0;rr<2;rr++){
      int r=b*8+wave*2+rr;
      float acc=0.0f;
      #pragma unroll
      for(int c4=0;c4<4;c4++) acc += d4(wih[rr][c4], *(const float4*)(er + c4*256 + lane*4));
      acc=wred_sum(acc);
      if(lane==0) pg[(size_t)t*4096+r]=acc+bias[rr];
    }
  }
}

// ================= encoder recurrent step (round-5 proven): cell-update(t-1) + Whh.h + pg =================
__global__ __launch_bounds__(256) void k_enc_rec(
  const float* __restrict__ Whh_f, const float* __restrict__ Whh_b,
  float* __restrict__ ws, int t)
{
  __shared__ __align__(16) float h_lds[1024];
  const int tid=threadIdx.x, b=blockIdx.x, wave=tid>>6, lane=tid&63;
  float* gates   = ws + WS_ENC_GATES;
  float* c_enc   = ws + WS_C_ENC;
  float* enc_outs= ws + WS_ENC_OUTS;
  const float* pg = ws + WS_PREG + (size_t)t*4096;
  if(t>0){
    const float* gp = gates + ((t-1)&1)*4096;
    const float* cp = c_enc + (t&1)*1024;        // c_{t-2}
    float* cw = c_enc + ((t-1)&1)*1024;          // c_{t-1}
    for(int u=tid;u<1024;u+=256){
      int base=(u<512)?0:2048, uu=(u<512)?u:(u-512);
      float ig=gp[base+uu], fg=gp[base+512+uu], gg=gp[base+1024+uu], og=gp[base+1536+uu];
      float cprev=(t==1)?0.0f:cp[u];
      float c=sigm(fg)*cprev+sigm(ig)*tanhf(gg);
      float h=sigm(og)*tanhf(c);
      h_lds[u]=h;
      if(b==0){ cw[u]=c; enc_outs[(size_t)(t-1)*1024+u]=h; }
    }
  }
  __syncthreads();
  float* gw = gates + (t&1)*4096;
  #pragma unroll
  for(int rr=0;rr<2;rr++){
    int r=b*8+wave*2+rr; bool isF=(r<2048); int rl=isF?r:(r-2048);
    if(t==0){
      if(lane==0) gw[r]=pg[r];
    } else {
      const float* hr=(isF?Whh_f:Whh_b)+(size_t)rl*HH;
      const float* hs=&h_lds[isF?0:512];
      float acc=0.0f;
      #pragma unroll
      for(int c2=0;c2<2;c2++){
        int m=c2*256+lane*4;
        acc += d4(*(const float4*)(hr+m), *(const float4*)(&hs[m]));
      }
      acc=wred_sum(acc);
      if(lane==0) gw[r]=pg[r]+acc;
    }
  }
}

// ================= fallback encoder step (round-4 proven) =================
__global__ __launch_bounds__(256) void k_enc_step(
  const int* __restrict__ xt, const float* __restrict__ emb,
  const float* __restrict__ Wih_f, const float* __restrict__ Whh_f,
  const float* __restrict__ bih_f, const float* __restrict__ bhh_f,
  const float* __restrict__ Wih_b, const float* __restrict__ Whh_b,
  const float* __restrict__ bih_b, const float* __restrict__ bhh_b,
  float* __restrict__ ws, int t)
{
  __shared__ __align__(16) float h_lds[1024];
  __shared__ __align__(16) float xe[1024];
  const int tid = threadIdx.x;
  float* gates   = ws + WS_ENC_GATES;
  float* c_enc   = ws + WS_C_ENC;
  float* enc_outs= ws + WS_ENC_OUTS;
  {
    const int tok = xt[t];
    const float* er = emb + (size_t)tok*EMBED;
    for(int j=tid;j<1024;j+=256) xe[j]=er[j];
  }
  if(t>0){
    const float* gp = gates + ((t-1)&1)*4096;
    const float* cp = c_enc + (t&1)*1024;
    float* cw = c_enc + ((t-1)&1)*1024;
    for(int u=tid;u<1024;u+=256){
      int base=(u<512)?0:2048, uu=(u<512)?u:(u-512);
      float ig=gp[base+uu], fg=gp[base+512+uu], gg=gp[base+1024+uu], og=gp[base+1536+uu];
      float cprev=(t==1)?0.0f:cp[u];
      float c=sigm(fg)*cprev+sigm(ig)*tanhf(gg);
      float h=sigm(og)*tanhf(c);
      h_lds[u]=h;
      if(blockIdx.x==0){ cw[u]=c; enc_outs[(size_t)(t-1)*1024+u]=h; }
    }
  }
  __syncthreads();
  float* gw = gates + (t&1)*4096;
  const int wave=tid>>6, lane=tid&63;
  for(int rr=0;rr<2;rr++){
    int r=blockIdx.x*8+wave*2+rr;
    bool isF=(r<2048); int rl=isF?r:(r-2048);
    const float* Wih=isF?Wih_f:Wih_b;
    const float* Whh=isF?Whh_f:Whh_b;
    float bias=isF?(bih_f[rl]+bhh_f[rl]):(bih_b[rl]+bhh_b[rl]);
    const float* wr=Wih+(size_t)rl*EMBED;
    float acc=0.0f;
    #pragma unroll
    for(int c4=0;c4<4;c4++){
      int m=c4*256+lane*4;
      acc += d4(*(const float4*)(wr+m), *(const float4*)(&xe[m]));
    }
    if(t>0){
      const float* hr=Whh+(size_t)rl*HH;
      const float* hs=&h_lds[isF?0:512];
      #pragma unroll
      for(int c2=0;c2<2;c2++){
        int m=c2*256+lane*4;
        acc += d4(*(const float4*)(hr+m), *(const float4*)(&hs[m]));
      }
    }
    acc=wred_sum(acc);
    if(lane==0) gw[r]=acc+bias;
  }
}

// ================= k_copy_final (round-5 proven) =================
__global__ __launch_bounds__(256) void k_copy_final(
  const float* __restrict__ emb,
  const float* __restrict__ copy_W, const float* __restrict__ copy_b,
  float* __restrict__ ws, float* __restrict__ out)
{
  __shared__ __align__(16) float hf[1024];
  const int tid=threadIdx.x, b=blockIdx.x, wave=tid>>6, lane=tid&63;
  float* gates = ws + WS_ENC_GATES;
  float* c_enc = ws + WS_C_ENC;
  float* enc_outs = ws + WS_ENC_OUTS;
  float* cenc = ws + WS_COPY_ENC;
  float* h_dec = ws + WS_H_DEC;
  float* c_dec = ws + WS_C_DEC;
  float* x_dec = ws + WS_X_DEC;
  {
    const float* gp = gates + ((L-1)&1)*4096;
    const float* cp = c_enc + ((L-2)&1)*1024;
    for(int u=tid;u<1024;u+=256){
      int base=(u<512)?0:2048, uu=(u<512)?u:(u-512);
      float ig=gp[base+uu], fg=gp[base+512+uu], gg=gp[base+1024+uu], og=gp[base+1536+uu];
      float c=sigm(fg)*cp[u]+sigm(ig)*tanhf(gg);
      float h=sigm(og)*tanhf(c);
      hf[u]=h;
      if(b==0){
        enc_outs[(size_t)(L-1)*1024+u]=h;
        h_dec[1024+u]=h;
        c_dec[1024+u]=c;
        out[u]=h;
      }
    }
    if(b==1) for(int j=tid;j<(ML-L)*1024;j+=256) enc_outs[(size_t)L*1024+j]=0.0f;
    if(b==2) for(int j=tid;j<1024;j+=256){
      x_dec[j]=emb[j];
      x_dec[1024+j]=0.0f;
      x_dec[2048+j]=0.0f;
    }
  }
  __syncthreads();
  int j = b*4 + wave;
  const float* wr = copy_W + (size_t)j*1024;
  float4 w0=*(const float4*)(wr+0*256+lane*4);
  float4 w1=*(const float4*)(wr+1*256+lane*4);
  float4 w2=*(const float4*)(wr+2*256+lane*4);
  float4 w3=*(const float4*)(wr+3*256+lane*4);
  float bj = copy_b[j];
  for(int k=0;k<L-1;k++){
    const float* er = enc_outs + (size_t)k*1024;
    float acc = d4(w0,*(const float4*)(er+0*256+lane*4))
              + d4(w1,*(const float4*)(er+1*256+lane*4))
              + d4(w2,*(const float4*)(er+2*256+lane*4))
              + d4(w3,*(const float4*)(er+3*256+lane*4));
    acc = wred_sum(acc);
    if(lane==0) cenc[(size_t)k*1024+j]=tanhf(acc+bj);
  }
  {
    float acc = d4(w0,*(const float4*)(&hf[0*256+lane*4]))
              + d4(w1,*(const float4*)(&hf[1*256+lane*4]))
              + d4(w2,*(const float4*)(&hf[2*256+lane*4]))
              + d4(w3,*(const float4*)(&hf[3*256+lane*4]));
    acc = wred_sum(acc);
    if(lane==0) cenc[(size_t)(L-1)*1024+j]=tanhf(acc+bj);
  }
  if(lane==0){
    float z=tanhf(0.0f+bj);
    for(int k=L;k<ML;k++) cenc[(size_t)k*1024+j]=z;
  }
}

// ================= k_gmat (round-7 proven): G = [W_sel;W_att] @ enc_outs^T =================
__global__ __launch_bounds__(256) void k_gmat(const float* __restrict__ Wih_d, float* __restrict__ ws)
{
  __shared__ __align__(16) float elds[16*1024];   // 64 KB
  const int tid=threadIdx.x, wave=tid>>6, lane=tid&63;
  const float* enc = ws + WS_ENC_OUTS;
  float* G = ws + WS_G;
  float4 w[4][4];
  int rg[4];
  #pragma unroll
  for(int q=0;q<4;q++){
    int r = blockIdx.x*16 + wave*4 + q;     // 0..8191
    rg[q]=r;
    const float* W = (r<4096) ? (Wih_d + (size_t)r*3072 + 1024)
                              : (Wih_d + (size_t)(r-4096)*3072 + 2048);
    #pragma unroll
    for(int c4=0;c4<4;c4++) w[q][c4]=*(const float4*)(W + c4*256 + lane*4);
  }
  for(int chunk=0;chunk<4;chunk++){
    __syncthreads();
    for(int idx=tid; idx<16*1024; idx+=256) elds[idx]=enc[(size_t)chunk*16*1024+idx];
    __syncthreads();
    for(int k=0;k<16;k++){
      #pragma unroll
      for(int q=0;q<4;q++){
        float acc=0.0f;
        #pragma unroll
        for(int c4=0;c4<4;c4++)
          acc += d4(w[q][c4], *(const float4*)(&elds[k*1024 + c4*256 + lane*4]));
        acc=wred_sum(acc);
        if(lane==0) G[(size_t)rg[q]*64 + chunk*16 + k]=acc;
      }
    }
  }
}

// ================= k_fin16: finalize step t-1 (16 blocks) + pc + 4 attn rows/block =================
__global__ __launch_bounds__(256) void k_fin16(
  const int* __restrict__ xt, const float* __restrict__ amask,
  const float* __restrict__ emb,
  const float* __restrict__ attn_W, const float* __restrict__ attn_b,
  float* __restrict__ ws, float* __restrict__ out, int t, int fin_only)
{
  __shared__ __align__(16) float dec_in[1024];
  __shared__ __align__(16) float hprev[1024];
  __shared__ float r_lm[256], r_sm[256], r_ky[256];
  __shared__ int r_ix[256];
  __shared__ float s_lmax, s_Z;
  __shared__ int s_act;
  const int tid=threadIdx.x, b=blockIdx.x, wave=tid>>6, lane=tid&63;
  float* h_dec=ws+WS_H_DEC;
  float* logits=ws+WS_LOGITS; float* parts=ws+WS_PARTS;
  float* attw_raw=ws+WS_ATTW; float* pcw=ws+WS_PC;

  // ---- parts reduce (round-4 proven: strided init guarantees every thread holds a finite lm) ----
  {
    float lm=-INFINITY, sm=0.0f, ky=-INFINITY; int ix=0x7fffffff;
    for(int i=tid;i<NPART;i+=256){
      const float4 p = *(const float4*)(parts+(size_t)i*4);
      float plm=p.x, psm=p.y, pky=p.z; int pix=__float_as_int(p.w);
      if(plm>lm){ sm = sm*__expf(lm-plm)+psm; lm=plm; }
      else sm += psm*__expf(plm-lm);
      if(pky>ky || (pky==ky && pix<ix)){ ky=pky; ix=pix; }
    }
    r_lm[tid]=lm; r_sm[tid]=sm; r_ky[tid]=ky; r_ix[tid]=ix;
    __syncthreads();
    for(int s=128;s;s>>=1){
      if(tid<s){
        float blm=r_lm[tid+s], bsm=r_sm[tid+s];
        float alm=r_lm[tid], a_sm=r_sm[tid];
        if(blm>alm){ r_sm[tid]=a_sm*__expf(alm-blm)+bsm; r_lm[tid]=blm; }
        else r_sm[tid]=a_sm+bsm*__expf(blm-alm);
        float bky=r_ky[tid+s]; int bix=r_ix[tid+s];
        if(bky>r_ky[tid] || (bky==r_ky[tid] && bix<r_ix[tid])){ r_ky[tid]=bky; r_ix[tid]=bix; }
      }
      __syncthreads();
    }
    if(tid==0){
      float lmax=r_lm[0]; float Z=r_sm[0];
      float bky=r_ky[0];
      int aidx = (bky==-INFINITY)?0:r_ix[0];
      bool isv = aidx<VOCAB;
      int kcl = aidx-VOCAB; kcl = kcl<0?0:(kcl>(L-1)?(L-1):kcl);
      int sp = xt[kcl];
      int action = isv? aidx : sp;
      if(b==0){
        float prob = amask[aidx]*__expf(logits[aidx]-lmax)/Z;
        if(!isv){
          int a2 = action<0?0:(action>(VOCAB-1)?(VOCAB-1):action);
          prob += amask[a2]*__expf(logits[a2]-lmax)/Z;
        }
        out[65*1024 + (t-1)] = prob;
        out[65*1024 + 64 + (t-1)] = (float)action;
        *(int*)(ws+WS_ACT) = action;
      }
      s_lmax=lmax; s_Z=Z; s_act=action;
    }
  }
  __syncthreads();
  if(fin_only) return;

  const int action = s_act;
  // pc (block 0 only; identical math to round 4)
  if(b==0 && tid<64){
    int k=tid;
    float v=__expf(logits[VOCAB+k]-s_lmax)/s_Z;
    int sp=(k<L)? xt[k] : -1;
    float m=(k>=1 && k<(L-1) && sp!=action)?1.0f:0.0f;
    float pv=v*m;
    float s=wred_sum(pv);
    pcw[k]=(s>0.0f)? pv/s : pv;
  }
  // dec_in (emb[action]) + h_{t-1}
  {
    int row = action<0 ? action+VOCAB : action;
    const float* er = emb + (size_t)row*EMBED;
    const float* hp = h_dec + ((t-1)&1)*1024;
    for(int j=tid;j<1024;j+=256){ dec_in[j]=er[j]; hprev[j]=hp[j]; }
  }
  __syncthreads();
  // attention logit row r = b*4 + wave (identical per-row math to round 4)
  {
    int r = b*4 + wave;
    const float* wr = attn_W + (size_t)r*2048;
    float acc=0.0f;
    #pragma unroll
    for(int c4=0;c4<4;c4++){
      int m=c4*256+lane*4;
      acc += d4(*(const float4*)(wr+m),      *(const float4*)(&dec_in[m]));
      acc += d4(*(const float4*)(wr+1024+m), *(const float4*)(&hprev[m]));
    }
    acc=wred_sum(acc);
    if(lane==0) attw_raw[r]=acc+attn_b[r];
  }
}

// ================= k_dec_gates3: prologue (softmax + emb[action]) + G-GEMV (round-7 proven core) =================
__global__ __launch_bounds__(256) void k_dec_gates3(
  const float* __restrict__ emb,
  const float* __restrict__ Wih_d, const float* __restrict__ Whh_d,
  const float* __restrict__ bih_d, const float* __restrict__ bhh_d,
  float* __restrict__ ws, int t)
{
  __shared__ __align__(16) float di[1024];
  __shared__ __align__(16) float hh[1024];
  __shared__ float pcs[64], aws[64];
  const int tid=threadIdx.x;
  float* h_dec=ws+WS_H_DEC; float* dg=ws+WS_DGATES;
  const float* G=ws+WS_G;
  if(t==0){
    for(int j=tid;j<1024;j+=256) di[j]=emb[j];       // sos
    if(tid<64){ pcs[tid]=0.0f; aws[tid]=0.0f; }
  } else {
    const int action = *(const int*)(ws+WS_ACT);
    const float* er = emb + (size_t)action*EMBED;
    for(int j=tid;j<1024;j+=256) di[j]=er[j];
    if(tid<64){
      pcs[tid]=(ws+WS_PC)[tid];
      float v=(ws+WS_ATTW)[tid];     // raw attn logits
      float mx=wred_max(v);
      float e=__expf(v-mx);
      float s=wred_sum(e);
      aws[tid]=e/s;
    }
  }
  {
    const float* hp=h_dec+((t+1)&1)*1024;   // h_{t-1}
    for(int j=tid;j<1024;j+=256) hh[j]=hp[j];
  }
  __syncthreads();
  const int wave=tid>>6, lane=tid&63;
  for(int rr=0;rr<2;rr++){
    int r=blockIdx.x*8+wave*2+rr;
    const float* wd=Wih_d+(size_t)r*3072;       // dec_in part (cols 0..1023)
    float acc=0.0f;
    #pragma unroll
    for(int c4=0;c4<4;c4++){
      int m=c4*256+lane*4;
      acc += d4(*(const float4*)(wd+m), *(const float4*)(&di[m]));
    }
    const float* hr=Whh_d+(size_t)r*1024;
    #pragma unroll
    for(int c4=0;c4<4;c4++){
      int m=c4*256+lane*4;
      acc += d4(*(const float4*)(hr+m), *(const float4*)(&hh[m]));
    }
    acc += G[(size_t)r*64+lane]*pcs[lane];
    acc += G[(size_t)(4096+r)*64+lane]*aws[lane];
    acc=wred_sum(acc);
    if(lane==0) dg[r]=acc+bih_d[r]+bhh_d[r];
  }
}

// ================= fallback (round-4) decoder kernels =================
__global__ __launch_bounds__(256) void k_dec_init(const float* __restrict__ emb, float* __restrict__ ws)
{
  float* x_dec=ws+WS_X_DEC;
  for(int j=threadIdx.x;j<1024;j+=256){
    x_dec[j]=emb[j];
    x_dec[1024+j]=0.0f;
    x_dec[2048+j]=0.0f;
  }
}

__global__ __launch_bounds__(256) void k_attn(
  const int* __restrict__ xt, const float* __restrict__ amask,
  const float* __restrict__ emb,
  const float* __restrict__ attn_W, const float* __restrict__ attn_b,
  float* __restrict__ ws, float* __restrict__ out, int t, int fin_only)
{
  __shared__ __align__(16) float dec_in[1024];
  __shared__ __align__(16) float hprev[1024];
  __shared__ float r_lm[256], r_sm[256], r_ky[256];
  __shared__ int r_ix[256];
  __shared__ float s_lmax, s_Z;
  __shared__ int s_act;
  const int tid=threadIdx.x;
  float* h_dec=ws+WS_H_DEC; float* x_dec=ws+WS_X_DEC;
  float* logits=ws+WS_LOGITS; float* parts=ws+WS_PARTS;
  float* attw_raw=ws+WS_ATTW; float* pcw=ws+WS_PC;
  {
    float lm=-INFINITY, sm=0.0f, ky=-INFINITY; int ix=0x7fffffff;
    for(int i=tid;i<NPART;i+=256){
      const float4 p = *(const float4*)(parts+(size_t)i*4);
      float plm=p.x, psm=p.y, pky=p.z; int pix=__float_as_int(p.w);
      if(plm>lm){ sm = sm*__expf(lm-plm)+psm; lm=plm; }
      else sm += psm*__expf(plm-lm);
      if(pky>ky || (pky==ky && pix<ix)){ ky=pky; ix=pix; }
    }
    r_lm[tid]=lm; r_sm[tid]=sm; r_ky[tid]=ky; r_ix[tid]=ix;
    __syncthreads();
    for(int s=128;s;s>>=1){
      if(tid<s){
        float blm=r_lm[tid+s], bsm=r_sm[tid+s];
        float alm=r_lm[tid], a_sm=r_sm[tid];
        if(blm>alm){ r_sm[tid]=a_sm*__expf(alm-blm)+bsm; r_lm[tid]=blm; }
        else r_sm[tid]=a_sm+bsm*__expf(blm-alm);
        float bky=r_ky[tid+s]; int bix=r_ix[tid+s];
        if(bky>r_ky[tid] || (bky==r_ky[tid] && bix<r_ix[tid])){ r_ky[tid]=bky; r_ix[tid]=bix; }
      }
      __syncthreads();
    }
    if(tid==0){
      float lmax=r_lm[0]; float Z=r_sm[0];
      float bky=r_ky[0];
      int aidx = (bky==-INFINITY)?0:r_ix[0];
      bool isv = aidx<VOCAB;
      int kcl = aidx-VOCAB; kcl = kcl<0?0:(kcl>(L-1)?(L-1):kcl);
      int sp = xt[kcl];
      int action = isv? aidx : sp;
      if(blockIdx.x==0){
        float prob = amask[aidx]*__expf(logits[aidx]-lmax)/Z;
        if(!isv){
          int a2 = action<0?0:(action>(VOCAB-1)?(VOCAB-1):action);
          prob += amask[a2]*__expf(logits[a2]-lmax)/Z;
        }
        out[65*1024 + (t-1)] = prob;
        out[65*1024 + 64 + (t-1)] = (float)action;
      }
      s_lmax=lmax; s_Z=Z; s_act=action;
    }
  }
  __syncthreads();
  if(fin_only) return;
  const int action = s_act;
  if(blockIdx.x==0 && tid<64){
    int k=tid;
    float v=__expf(logits[VOCAB+k]-s_lmax)/s_Z;
    int sp=(k<L)? xt[k] : -1;
    float m=(k>=1 && k<(L-1) && sp!=action)?1.0f:0.0f;
    float pv=v*m;
    float s=wred_sum(pv);
    pcw[k]=(s>0.0f)? pv/s : pv;
  }
  {
    int row = action<0 ? action+VOCAB : action;
    const float* er = emb + (size_t)row*EMBED;
    const float* hp = h_dec + ((t-1)&1)*1024;
    for(int j=tid;j<1024;j+=256){
      float v=er[j];
      dec_in[j]=v; hprev[j]=hp[j];
      if(blockIdx.x==0) x_dec[j]=v;
    }
  }
  __syncthreads();
  if(tid<64){
    const int lane=tid;
    const float* wr = attn_W + (size_t)blockIdx.x*2048;
    float acc=0.0f;
    #pragma unroll
    for(int c4=0;c4<4;c4++){
      int m=c4*256+lane*4;
      acc += d4(*(const float4*)(wr+m),      *(const float4*)(&dec_in[m]));
      acc += d4(*(const float4*)(wr+1024+m), *(const float4*)(&hprev[m]));
    }
    acc=wred_sum(acc);
    if(lane==0) attw_raw[blockIdx.x]=acc+attn_b[blockIdx.x];
  }
}

__global__ __launch_bounds__(256) void k_prep(float* __restrict__ ws)
{
  __shared__ float attw_s[64], pc_s[64];
  const int tid=threadIdx.x;
  float* enc_outs=ws+WS_ENC_OUTS; float* x_dec=ws+WS_X_DEC;
  float* attw_raw=ws+WS_ATTW; float* pcw=ws+WS_PC;
  if(tid<64){
    float v=attw_raw[tid];
    float mx=wred_max(v);
    float e=__expf(v-mx);
    float s=wred_sum(e);
    attw_s[tid]=e/s;
    pc_s[tid]=pcw[tid];
  }
  __syncthreads();
  int j=blockIdx.x*256+tid;
  float aA=0.0f, aS=0.0f;
  for(int k=0;k<ML;k++){
    float e=enc_outs[(size_t)k*1024+j];
    aA += attw_s[k]*e;
    aS += pc_s[k]*e;
  }
  x_dec[1024+j]=aS;
  x_dec[2048+j]=aA;
}

__global__ __launch_bounds__(256) void k_dec_gates(
  const float* __restrict__ Wih_d, const float* __restrict__ Whh_d,
  const float* __restrict__ bih_d, const float* __restrict__ bhh_d,
  float* __restrict__ ws, int t)
{
  __shared__ __align__(16) float x_lds[4096];
  const int tid=threadIdx.x;
  float* x_dec=ws+WS_X_DEC; float* h_dec=ws+WS_H_DEC; float* dg=ws+WS_DGATES;
  for(int j=tid;j<3072;j+=256) x_lds[j]=x_dec[j];
  {
    const float* hp=h_dec+((t+1)&1)*1024;
    for(int j=tid;j<1024;j+=256) x_lds[3072+j]=hp[j];
  }
  __syncthreads();
  const int wave=tid>>6, lane=tid&63;
  for(int rr=0;rr<2;rr++){
    int r=blockIdx.x*8+wave*2+rr;
    const float* wr=Wih_d+(size_t)r*3072;
    float acc=0.0f;
    #pragma unroll
    for(int c4=0;c4<12;c4++){
      int m=c4*256+lane*4;
      acc += d4(*(const float4*)(wr+m), *(const float4*)(&x_lds[m]));
    }
    const float* hr=Whh_d+(size_t)r*1024;
    #pragma unroll
    for(int c4=0;c4<4;c4++){
      int m=c4*256+lane*4;
      acc += d4(*(const float4*)(hr+m), *(const float4*)(&x_lds[3072+m]));
    }
    acc=wred_sum(acc);
    if(lane==0) dg[r]=acc+bih_d[r]+bhh_d[r];
  }
}

// ================= decoder gen (unchanged, both paths) =================
__global__ __launch_bounds__(256) void k_dec_gen(
  const float* __restrict__ gen_W, const float* __restrict__ gen_b,
  const float* __restrict__ amask,
  float* __restrict__ ws, float* __restrict__ out, int t)
{
  __shared__ __align__(16) float h_lds[1024];
  __shared__ float w_lm[4], w_sm[4], w_ky[4];
  __shared__ int w_ix[4];
  const int tid=threadIdx.x;
  float* dg=ws+WS_DGATES;
  float* c_dec=ws+WS_C_DEC; float* h_dec=ws+WS_H_DEC;
  float* logits=ws+WS_LOGITS; float* parts=ws+WS_PARTS;
  float* cenc=ws+WS_COPY_ENC;
  {
    const float* cp=c_dec+((t+1)&1)*1024;
    float* cw=c_dec+(t&1)*1024;
    float* hw=h_dec+(t&1)*1024;
    for(int u=tid;u<1024;u+=256){
      float ig=dg[u], fg=dg[1024+u], gg=dg[2048+u], og=dg[3072+u];
      float c=sigm(fg)*cp[u]+sigm(ig)*tanhf(gg);
      float h=sigm(og)*tanhf(c);
      h_lds[u]=h;
      if(blockIdx.x==0){ cw[u]=c; hw[u]=h; out[(size_t)(t+1)*1024+u]=h; }
    }
  }
  __syncthreads();
  const int wave=tid>>6, lane=tid&63;
  const int b=blockIdx.x;
  const bool isGen=(b<500);
  const int rbase = isGen ? (b*64+wave*16) : (VOCAB+wave*16);
  float lv[16];
  #pragma unroll
  for(int rr=0;rr<16;rr++){
    const float* wr = isGen ? gen_W+(size_t)(rbase+rr)*1024
                            : cenc +(size_t)(rbase-VOCAB+rr)*1024;
    float acc=0.0f;
    #pragma unroll
    for(int c4=0;c4<4;c4++){
      int m=c4*256+lane*4;
      acc += d4(*(const float4*)(wr+m), *(const float4*)(&h_lds[m]));
    }
    acc=wred_sum(acc);
    lv[rr] = isGen ? acc+gen_b[rbase+rr] : acc;
  }
  if(lane==0){
    float lm=-INFINITY, ky=-INFINITY; int ix=0;
    #pragma unroll
    for(int rr=0;rr<16;rr++){
      int gi=rbase+rr;
      logits[gi]=lv[rr];
      lm=fmaxf(lm,lv[rr]);
      float mk=amask[gi];
      float kk = (mk>0.0f)? (lv[rr]+__logf(mk)) : -INFINITY;
      if(kk>ky){ ky=kk; ix=gi; }
    }
    float sm=0.0f;
    #pragma unroll
    for(int rr=0;rr<16;rr++) sm += __expf(lv[rr]-lm);
    w_lm[wave]=lm; w_sm[wave]=sm; w_ky[wave]=ky; w_ix[wave]=ix;
  }
  __syncthreads();
  if(tid==0){
    float lm=w_lm[0], sm=w_sm[0], ky=w_ky[0]; int ix=w_ix[0];
    for(int w=1;w<4;w++){
      float blm=w_lm[w], bsm=w_sm[w];
      if(blm>lm){ sm=sm*__expf(lm-blm)+bsm; lm=blm; }
      else sm += bsm*__expf(blm-lm);
      if(w_ky[w]>ky || (w_ky[w]==ky && w_ix[w]<ix)){ ky=w_ky[w]; ix=w_ix[w]; }
    }
    float4 p; p.x=lm; p.y=sm; p.z=ky; p.w=__int_as_float(ix);
    *(float4*)(parts+(size_t)blockIdx.x*4)=p;
  }
}

extern "C" void kernel_launch(void* const* d_in, const int* in_sizes, int n_in,
                              void* d_out, int out_size, void* d_ws, size_t ws_size,
                              hipStream_t stream)
{
  const int*   xt     = (const int*)d_in[0];
  const float* amask  = (const float*)d_in[1];
  const float* emb    = (const float*)d_in[2];
  const float* Wih_f  = (const float*)d_in[3];
  const float* Whh_f  = (const float*)d_in[4];
  const float* bih_f  = (const float*)d_in[5];
  const float* bhh_f  = (const float*)d_in[6];
  const float* Wih_b  = (const float*)d_in[7];
  const float* Whh_b  = (const float*)d_in[8];
  const float* bih_b  = (const float*)d_in[9];
  const float* bhh_b  = (const float*)d_in[10];
  const float* Wih_d  = (const float*)d_in[11];
  const float* Whh_d  = (const float*)d_in[12];
  const float* bih_d  = (const float*)d_in[13];
  const float* bhh_d  = (const float*)d_in[14];
  const float* attn_W = (const float*)d_in[15];
  const float* attn_b = (const float*)d_in[16];
  const float* gen_W  = (const float*)d_in[17];
  const float* gen_b  = (const float*)d_in[18];
  const float* copy_W = (const float*)d_in[19];
  const float* copy_b = (const float*)d_in[20];
  float* out=(float*)d_out;
  float* ws =(float*)d_ws;

  const bool hasG    = ws_size >= (size_t)WS_G_END*sizeof(float);
  const bool hasPreg = ws_size >= (size_t)WS_END*sizeof(float);

  if(hasPreg){
    k_enc_pre2<<<512,256,0,stream>>>(xt,emb,Wih_f,bih_f,bhh_f,Wih_b,bih_b,bhh_b,ws);
    for(int t=0;t<L;t++)
      k_enc_rec<<<512,256,0,stream>>>(Whh_f,Whh_b,ws,t);
  } else {
    for(int t=0;t<L;t++)
      k_enc_step<<<512,256,0,stream>>>(xt,emb,Wih_f,Whh_f,bih_f,bhh_f,Wih_b,Whh_b,bih_b,bhh_b,ws,t);
  }
  k_copy_final<<<256,256,0,stream>>>(emb,copy_W,copy_b,ws,out);

  if(hasG){
    k_gmat<<<512,256,0,stream>>>(Wih_d,ws);
    k_dec_gates3<<<512,256,0,stream>>>(emb,Wih_d,Whh_d,bih_d,bhh_d,ws,0);
    k_dec_gen   <<<501,256,0,stream>>>(gen_W,gen_b,amask,ws,out,0);
    for(int t=1;t<ML;t++){
      k_fin16     <<<16,256,0,stream>>>(xt,amask,emb,attn_W,attn_b,ws,out,t,0);
      k_dec_gates3<<<512,256,0,stream>>>(emb,Wih_d,Whh_d,bih_d,bhh_d,ws,t);
      k_dec_gen   <<<501,256,0,stream>>>(gen_W,gen_b,amask,ws,out,t);
    }
    k_fin16<<<1,256,0,stream>>>(xt,amask,emb,attn_W,attn_b,ws,out,ML,1);
  } else {
    k_dec_init<<<1,256,0,stream>>>(emb,ws);
    k_dec_gates<<<512,256,0,stream>>>(Wih_d,Whh_d,bih_d,bhh_d,ws,0);
    k_dec_gen  <<<501,256,0,stream>>>(gen_W,gen_b,amask,ws,out,0);
    for(int t=1;t<ML;t++){
      k_attn     <<<64,256,0,stream>>>(xt,amask,emb,attn_W,attn_b,ws,out,t,0);
      k_prep     <<<4,256,0,stream>>>(ws);
      k_dec_gates<<<512,256,0,stream>>>(Wih_d,Whh_d,bih_d,bhh_d,ws,t);
      k_dec_gen  <<<501,256,0,stream>>>(gen_W,gen_b,amask,ws,out,t);
    }
    k_attn<<<1,256,0,stream>>>(xt,amask,emb,attn_W,attn_b,ws,out,ML,1);
  }
}